// Round 1
// baseline (578.385 us; speedup 1.0000x reference)
//
#include <hip/hip_runtime.h>

// DCT as flat batched GEMM: out[p][f] = sum_s x[p][s] * K[s][f]
// p = 0..393215 (64-float contiguous chunks of the input), K is 64x64 fp32.
//
// Memory-bound problem (AI = 16 FLOP/B < 25 FLOP/B balance) -> fp32 VALU path,
// target ~32 us at 6.3 TB/s.
//
// Layout: lane = f. Each lane holds K column f in 64 VGPRs. Block stages
// 64 patches (16 KB) into LDS coalesced; each wave broadcasts-reads patch rows
// (all lanes same LDS address = conflict-free broadcast) and does 64 v_fmac
// per patch. Output store: 64 consecutive floats per wave = coalesced.

#define PATCHES_PER_BLOCK 64
#define THREADS 256

__global__ __launch_bounds__(THREADS, 4)  // 4 blocks/CU, VGPR cap 128 (kcol=64 + temps fits)
void dct_kernel(const float* __restrict__ x,
                const float* __restrict__ K,
                float* __restrict__ out) {
    __shared__ float lds_x[PATCHES_PER_BLOCK * 64];  // 16 KB

    const int tid  = threadIdx.x;
    const int lane = tid & 63;
    const int wave = tid >> 6;

    // Load K column `lane` into registers: K[s*64 + lane], coalesced per s,
    // 16 KB total -> L2-resident after first blocks.
    float kcol[64];
#pragma unroll
    for (int s = 0; s < 64; ++s) kcol[s] = K[s * 64 + lane];

    const long long tile_patch = (long long)blockIdx.x * PATCHES_PER_BLOCK;

    // Stage 64 patches * 64 floats = 1024 float4; 4 per thread, coalesced.
    const float4* src = (const float4*)(x + tile_patch * 64);
    float4* dst = (float4*)lds_x;
#pragma unroll
    for (int i = 0; i < 4; ++i) {
        dst[tid + i * THREADS] = src[tid + i * THREADS];
    }
    __syncthreads();

    // Each wave computes 16 patches.
    const int p0 = wave * 16;
    float* outp = out + (tile_patch + p0) * 64;

    for (int p = 0; p < 16; ++p) {
        const float* xr = lds_x + (p0 + p) * 64;  // wave-uniform address -> broadcast
        float acc = 0.0f;
#pragma unroll
        for (int s = 0; s < 64; ++s) {
            acc = fmaf(xr[s], kcol[s], acc);
        }
        outp[p * 64 + lane] = acc;
    }
}

extern "C" void kernel_launch(void* const* d_in, const int* in_sizes, int n_in,
                              void* d_out, int out_size, void* d_ws, size_t ws_size,
                              hipStream_t stream) {
    const float* x = (const float*)d_in[0];   // (8,3,1024,1024) fp32
    const float* K = (const float*)d_in[1];   // (64,64) fp32
    float* out = (float*)d_out;

    const int total = in_sizes[0];            // 25165824
    const int num_patches = total / 64;       // 393216
    const int blocks = num_patches / PATCHES_PER_BLOCK;  // 6144, divides exactly

    dct_kernel<<<blocks, THREADS, 0, stream>>>(x, K, out);
}

// Round 2
// 231.036 us; speedup vs baseline: 2.5034x; 2.5034x over previous
//
#include <hip/hip_runtime.h>

// DCT as flat GEMM: out[p][f] = sum_s x[p][s] * K[s][f]
// p = 0..393215 (64-float contiguous patches), K is 64x64 fp32.
//
// R1 post-mortem: kcol[64] per-lane array spilled to scratch (VGPR_Count=64,
// WRITE_SIZE 5x output, FETCH 12x input, VALUBusy 12%). Fix: chunk K into 4
// groups of 16 so live register demand is kc[16] + acc[16] (~56 VGPRs),
// structurally spill-free. K-chunk loop is '#pragma unroll 1' so the compiler
// cannot re-hoist all 64 K loads into one live range.
//
// Per wave (16 patches): x via LDS broadcast float4 reads (all lanes same
// address -> conflict-free broadcast), K chunk from global (16 KB, L2-hot,
// coalesced: lane f reads K[s*64+f]). Stores: 256 B contiguous per wave.

#define PATCHES_PER_BLOCK 64
#define THREADS 256

__global__ __launch_bounds__(THREADS, 2)
void dct_kernel(const float* __restrict__ x,
                const float* __restrict__ K,
                float* __restrict__ out) {
    __shared__ float lds_x[PATCHES_PER_BLOCK * 64];  // 16 KB

    const int tid  = threadIdx.x;
    const int lane = tid & 63;
    const int wave = tid >> 6;

    const long long tile_patch = (long long)blockIdx.x * PATCHES_PER_BLOCK;

    // Stage 64 patches * 64 floats = 1024 float4; 4 per thread, coalesced.
    const float4* src = (const float4*)(x + tile_patch * 64);
    float4* dst = (float4*)lds_x;
#pragma unroll
    for (int i = 0; i < 4; ++i) {
        dst[tid + i * THREADS] = src[tid + i * THREADS];
    }
    __syncthreads();

    // Each wave computes 16 patches; lane = output frequency f.
    const int p0 = wave * 16;

    float acc[16];
#pragma unroll
    for (int p = 0; p < 16; ++p) acc[p] = 0.0f;

#pragma unroll 1   // keep kc[16] live range per-chunk; do NOT hoist all of K
    for (int c = 0; c < 4; ++c) {
        float kc[16];
#pragma unroll
        for (int i = 0; i < 16; ++i) {
            kc[i] = K[(c * 16 + i) * 64 + lane];   // coalesced 256 B, L2-hot
        }
#pragma unroll
        for (int p = 0; p < 16; ++p) {
            const float4* xr =
                (const float4*)(lds_x + (p0 + p) * 64 + c * 16);  // wave-uniform -> broadcast
            float4 x0 = xr[0], x1 = xr[1], x2 = xr[2], x3 = xr[3];
            float a = acc[p];
            a = fmaf(x0.x, kc[0],  a);
            a = fmaf(x0.y, kc[1],  a);
            a = fmaf(x0.z, kc[2],  a);
            a = fmaf(x0.w, kc[3],  a);
            a = fmaf(x1.x, kc[4],  a);
            a = fmaf(x1.y, kc[5],  a);
            a = fmaf(x1.z, kc[6],  a);
            a = fmaf(x1.w, kc[7],  a);
            a = fmaf(x2.x, kc[8],  a);
            a = fmaf(x2.y, kc[9],  a);
            a = fmaf(x2.z, kc[10], a);
            a = fmaf(x2.w, kc[11], a);
            a = fmaf(x3.x, kc[12], a);
            a = fmaf(x3.y, kc[13], a);
            a = fmaf(x3.z, kc[14], a);
            a = fmaf(x3.w, kc[15], a);
            acc[p] = a;
        }
    }

    // Store: per wave, 64 consecutive floats per patch = coalesced 256 B.
    float* outp = out + (tile_patch + p0) * 64;
#pragma unroll
    for (int p = 0; p < 16; ++p) {
        outp[p * 64 + lane] = acc[p];
    }
}

extern "C" void kernel_launch(void* const* d_in, const int* in_sizes, int n_in,
                              void* d_out, int out_size, void* d_ws, size_t ws_size,
                              hipStream_t stream) {
    const float* x = (const float*)d_in[0];   // (8,3,1024,1024) fp32
    const float* K = (const float*)d_in[1];   // (64,64) fp32
    float* out = (float*)d_out;

    const int total = in_sizes[0];            // 25165824
    const int num_patches = total / 64;       // 393216
    const int blocks = num_patches / PATCHES_PER_BLOCK;  // 6144

    dct_kernel<<<blocks, THREADS, 0, stream>>>(x, K, out);
}

// Round 3
// 217.265 us; speedup vs baseline: 2.6621x; 1.0634x over previous
//
#include <hip/hip_runtime.h>

// out[p][f] = sum_s x[p][s] * K[s][f];  P = 393216 patches, 64x64 K.
//
// R2 post-mortem: lane=f forced LDS *broadcast* reads (16 useful B per ~12-cyc
// ds_read_b128). 6144 blocks x 1024 b128 x 12cyc / 256 CU = 123 us == measured
// 118 us. Structural fix: lane = patch.
//  - x[p][s]: LDS pad-65 rows, bank (lane+s)%32 -> 2-way (free).
//  - K[s][f]: wave-uniform address -> scalar s_load_dwordx16, feeds
//    v_fmac_f32 v,s,v. No LDS, no VGPRs for K; scalar-cache hot (16 KB).
//  - acc[32] per f-chunk (2 chunks) -> 32 indep FMA chains = full ILP from a
//    single wave; structurally spill-free (R1 lesson: no 64-elem arrays).
//  - Stores transposed through a small pad-33 LDS buffer -> coalesced
//    (2 x 128B segments per store instr); all patterns <=2-way banked.
//
// Cycle model/CU: FMA 20.5 us, LDS 18.6 us (parallel pipe), HBM 24-32 us
// -> predict 30-40 us.

#define THREADS 128   // 2 waves
#define PPB     128   // patches per block
#define XS      65    // x slab row stride (floats): odd -> conflict-free b32
#define TS      33    // transpose row stride

__global__ __attribute__((amdgpu_flat_work_group_size(THREADS, THREADS),
                          amdgpu_waves_per_eu(2, 4)))   // cap spill-chasing (R1)
void dct_kernel(const float* __restrict__ x,
                const float* __restrict__ Kmat,
                float* __restrict__ out) {
    __shared__ float lx[PPB * XS];      // 33,280 B
    __shared__ float tr[2 * 64 * TS];   // 16,896 B ; total 50,176 -> 3 blk/CU

    const int tid  = threadIdx.x;
    const int lane = tid & 63;
    const int wave = tid >> 6;
    const long long tile = (long long)blockIdx.x * PPB;

    // ---- stage 128 patches (8192 floats) coalesced; b32 LDS writes (pad) ----
    const float4* src = (const float4*)(x + tile * 64);
#pragma unroll
    for (int i = 0; i < 16; ++i) {
        int f4 = tid + i * THREADS;          // 0..2047
        float4 v = src[f4];
        int p = f4 >> 4;
        int s = (f4 & 15) << 2;
        float* d = &lx[p * XS + s];
        d[0] = v.x; d[1] = v.y; d[2] = v.z; d[3] = v.w;
    }
    __syncthreads();

    // ---- compute: lane owns patch (wave*64 + lane) ----
    const float* xrow = &lx[(wave * 64 + lane) * XS];
    float* trw = &tr[wave * 64 * TS];        // per-wave private region

    const int l5 = lane >> 5;                // 0/1: which of 2 patches per store
    const int f0 = lane & 31;                // f within chunk

#pragma unroll 1                             // keep acc live range per-chunk
    for (int fc = 0; fc < 2; ++fc) {
        float acc[32];
#pragma unroll
        for (int j = 0; j < 32; ++j) acc[j] = 0.f;

#pragma unroll 2
        for (int s = 0; s < 64; ++s) {
            float xs = xrow[s];                          // ds_read_b32, 2-way
            const float* Kr = Kmat + s * 64 + fc * 32;   // uniform -> s_load
#pragma unroll
            for (int j = 0; j < 32; ++j)
                acc[j] = fmaf(xs, Kr[j], acc[j]);        // v_fmac v,s,v
        }

        // ---- transpose within own wave (in-order DS, no barrier) ----
#pragma unroll
        for (int j = 0; j < 32; ++j)
            trw[lane * TS + j] = acc[j];     // banks (lane+j)%32: 2-way free

        // lane l stores f = fc*32+f0 of patches p = pit*2 + l5 -> coalesced
        float* ob = out + (tile + wave * 64) * 64 + fc * 32 + f0;
#pragma unroll
        for (int pit = 0; pit < 32; ++pit) {
            int p = pit * 2 + l5;
            ob[p * 64] = trw[p * TS + f0];   // banks (p+f0)%32: 2-way free
        }
    }
}

extern "C" void kernel_launch(void* const* d_in, const int* in_sizes, int n_in,
                              void* d_out, int out_size, void* d_ws, size_t ws_size,
                              hipStream_t stream) {
    const float* x = (const float*)d_in[0];   // (8,3,1024,1024) fp32
    const float* K = (const float*)d_in[1];   // (64,64) fp32
    float* out = (float*)d_out;

    const int total = in_sizes[0];            // 25,165,824
    const int num_patches = total / 64;       // 393,216
    const int blocks = num_patches / PPB;     // 3072, exact

    dct_kernel<<<blocks, THREADS, 0, stream>>>(x, K, out);
}